// Round 18
// baseline (108.152 us; speedup 1.0000x reference)
//
#include <hip/hip_runtime.h>
#include <math.h>

#define NB 32
#define NP 24656
#define NO 16
#define NC 81
#define ND 85   // 4 + NC
#define THRESH_F 0.5f
#define NEGPOS_I 3
#define VAR0_F 0.1f
#define VAR1_F 0.2f
#define NEG_HUGE -1e30f

#define BPCNT (NB * NP)
#define MBLK2 25         // k_match blocks per batch row = ceil(NP/1024)
#define CHB32 771        // 32-row chunks per batch row = ceil(NP/32)
#define SPB2 56          // k_main blocks per batch row (56*32 = 1792 = 7/CU)
#define CB32 11264       // staged bytes per chunk = 11 x 1024 (>= 32*85*4)

typedef unsigned long long u64;

// ---------------------------------------------------------------- match
// Slim: mcand-only (best-truth moved into k_main — it's row-local).
// LDS tree-reduce (R17, replaced 192 ds_bpermute/thread).
__global__ __launch_bounds__(256) void k_match(
    const float* __restrict__ tboxes, const float* __restrict__ priors,
    u64* __restrict__ mcand,
    int* __restrict__ npos, float* __restrict__ accB, int* __restrict__ done) {
    const int b = blockIdx.y, bx = blockIdx.x, tid = threadIdx.x;
    __shared__ float tb[NO * 4];
    __shared__ u64 kbuf[NO][256];   // 32 KiB
    __shared__ u64 pbuf[NO][16];    // 2 KiB
    if (bx == 0 && b == 0) {  // merged k_init
        if (tid < NB) npos[tid] = 0;
        if (tid < 2 * NB) accB[tid] = 0.f;
        if (tid == 0) *done = 0;
    }
    if (tid < NO * 4) tb[tid] = tboxes[b * NO * 4 + tid];
    __syncthreads();

    const int p0 = bx * 1024 + tid * 4;
    float pl[4], pt[4], prr[4], pbm[4], pa[4];
    bool pv[4];
#pragma unroll
    for (int j = 0; j < 4; ++j) {
        const int p = p0 + j;
        pv[j] = (p < NP);
        const float4 q = pv[j] ? ((const float4*)priors)[p]
                               : make_float4(0.f, 0.f, 1.f, 1.f);
        pl[j] = q.x - q.z * 0.5f; pt[j] = q.y - q.w * 0.5f;
        prr[j] = q.x + q.z * 0.5f; pbm[j] = q.y + q.w * 0.5f;
        pa[j] = (prr[j] - pl[j]) * (pbm[j] - pt[j]);
    }
    for (int o = 0; o < NO; ++o) {
        const float al = tb[o * 4], at = tb[o * 4 + 1];
        const float ar = tb[o * 4 + 2], ab = tb[o * 4 + 3];
        const float aarea = (ar - al) * (ab - at);
        u64 kmax = 0ull;
#pragma unroll
        for (int j = 0; j < 4; ++j) {
            float iw = fminf(ar, prr[j]) - fmaxf(al, pl[j]); iw = fmaxf(iw, 0.f);
            float ih = fminf(ab, pbm[j]) - fmaxf(at, pt[j]); ih = fmaxf(ih, 0.f);
            const float inter = iw * ih;
            const float iou = inter / (aarea + pa[j] - inter);
            if (pv[j]) {
                const u64 key = ((u64)__float_as_uint(iou) << 32) |
                                (u64)(0xFFFFFFFFu - (unsigned)(p0 + j));
                kmax = (key > kmax) ? key : kmax;
            }
        }
        kbuf[o][tid] = kmax;          // no cross-lane ops
    }
    __syncthreads();
    {   // stage B: 256 threads = (o, seg); strided subset avoids bank pileup
        const int o = tid >> 4, seg = tid & 15;
        u64 m = kbuf[o][seg];
#pragma unroll
        for (int i = 1; i < 16; ++i) {
            const u64 v = kbuf[o][i * 16 + seg];
            m = (v > m) ? v : m;
        }
        pbuf[o][seg] = m;
    }
    __syncthreads();
    if (tid < NO) {  // stage C
        u64 m = pbuf[tid][0];
#pragma unroll
        for (int i = 1; i < 16; ++i) {
            const u64 v = pbuf[tid][i];
            m = (v > m) ? v : m;
        }
        mcand[((size_t)(b * NO + tid)) * MBLK2 + bx] = m;
    }
}

// ---------------------------------------------------------------- stage (reg)
__device__ __forceinline__ void stage_load(float4* vreg,
                                           const char* __restrict__ gpred,
                                           int b, int r0, int lane) {
    const size_t off = ((size_t)b * NP + r0) * 340ull;
    const char* g = gpred + off;
    const bool unsafe = (b == NB - 1) && (r0 + 34 > NP);
    if (!unsafe) {
#pragma unroll
        for (int k = 0; k < 11; ++k)
            vreg[k] = *(const float4*)(g + k * 1024 + lane * 16);
    } else {
        const int nf4 = (NP - r0) * ND / 4;  // tail: 16 rows -> 340 float4
        const float4* gs = (const float4*)g;
#pragma unroll
        for (int k = 0; k < 11; ++k) {
            const int idx = k * 64 + lane;
            vreg[k] = (idx < nf4) ? gs[idx]
                                  : make_float4(0.f, 0.f, 0.f, 0.f);
        }
    }
}

__device__ __forceinline__ void stage_write(char* buf, const float4* vreg,
                                            int lane) {
#pragma unroll
    for (int k = 0; k < 11; ++k)
        *(float4*)(buf + k * 1024 + lane * 16) = vreg[k];
}

// ---------------------------------------------------------------- main fused
// R18: best-truth matching fused in (row-local). Lane pair splits the 16
// IoUs (h==0: o 0..7, h==1: o 8..15); combine via one shfl_xor(1) with
// first-max tie-break (larger IoU, then smaller o == jnp.argmax order).
// bt2 array eliminated (-12.6MB W, -12.6MB R).
__global__ __launch_bounds__(64) void k_main(
    const float* __restrict__ pred, const float* __restrict__ tboxes,
    const int* __restrict__ tlabels, const float* __restrict__ priors,
    const u64* __restrict__ mcand,
    float* __restrict__ lr, int* __restrict__ npos, float* __restrict__ accB) {
    __shared__ char smem[2][CB32];
    __shared__ float tbs[NO * 4];

    const int b = blockIdx.y;
    const int span = blockIdx.x;
    const int lane = threadIdx.x;
    const size_t bbase = (size_t)b * NP;
    const char* gpred = (const char*)pred;

    char* cur = smem[0];
    char* nxt = smem[1];

    const int rho = lane >> 1;   // row in chunk 0..31
    const int h = lane & 1;      // half: 0 -> slots 1..11, 1 -> slots 11..21
    const int c0 = rho & 3;
    const int Ab = 16 * (21 * rho + (rho >> 2));  // byte of aligned slot 0
    const int sbase = h ? 11 : 1;

    tbs[lane] = tboxes[b * NO * 4 + lane];  // 64 threads = 64 floats

    // prologue: per-o best prior for this b (lanes 0..15), broadcast to all
    u64 pbk = 0ull;
    if (lane < NO) {
        const u64* c = mcand + (size_t)(b * NO + lane) * MBLK2;
        for (int i = 0; i < MBLK2; ++i) {
            const u64 v = c[i];
            pbk = (v > pbk) ? v : pbk;
        }
    }
    int p16[NO];
#pragma unroll
    for (int j = 0; j < NO; ++j) {
        const u64 kj = __shfl(pbk, j, 64);
        p16[j] = (int)(0xFFFFFFFFu - (unsigned)(kj & 0xFFFFFFFFull));
    }

    float my_ll = 0.f, my_ce = 0.f;
    int my_np = 0;

    int chunk = span;
    int next_chunk = chunk + SPB2;
    {
        float4 vreg[11];
        stage_load(vreg, gpred, b, chunk * 32, lane);
        stage_write(cur, vreg, lane);
    }

    while (chunk < CHB32) {
        float4 vreg[11];
        const bool have_next = (next_chunk < CHB32);
        if (have_next)
            stage_load(vreg, gpred, b, next_chunk * 32, lane);  // issue early

        const int r0 = chunk * 32;
        const int nrows = min(32, NP - r0);
        const int p = r0 + rho;
        const bool rok = (rho < nrows);

        float4 v[11];
#pragma unroll
        for (int k = 0; k < 11; ++k)
            v[k] = *(const float4*)(cur + Ab + 16 * (sbase + k));

        float vals[44];
#pragma unroll
        for (int k = 0; k < 11; ++k) {
            const float xs[4] = {v[k].x, v[k].y, v[k].z, v[k].w};
#pragma unroll
            for (int t = 0; t < 4; ++t) {
                bool ok;
                if (k == 0)
                    ok = h ? false : (t >= c0);
                else if (k == 10)
                    ok = h ? (t <= c0) : true;
                else
                    ok = true;
                vals[4 * k + t] = ok ? xs[t] : NEG_HUGE;
            }
        }
        float mA = vals[0], mB = vals[1];
#pragma unroll
        for (int j = 2; j < 44; j += 2) {
            mA = fmaxf(mA, vals[j]);
            mB = fmaxf(mB, vals[j + 1]);
        }
        float m = fmaxf(mA, mB);
        m = fmaxf(m, __shfl_xor(m, 1, 64));  // pair (row) max

        float sA = 0.f, sB = 0.f;
#pragma unroll
        for (int j = 0; j < 44; j += 2) {
            sA += __expf(vals[j] - m);
            sB += __expf(vals[j + 1] - m);
        }
        float ssum = sA + sB;
        ssum += __shfl_xor(ssum, 1, 64);     // pair (row) sum
        const float lse = m + __logf(ssum);

        // fused best-truth: this lane covers o in [h*8, h*8+8)
        float bv = -1.f;
        int bi = 0;
        {
            const float4 pq = rok ? *((const float4*)priors + p)
                                  : make_float4(0.f, 0.f, 1.f, 1.f);
            const float prl = pq.x - pq.z * 0.5f, prt = pq.y - pq.w * 0.5f;
            const float prr2 = pq.x + pq.z * 0.5f, prb = pq.y + pq.w * 0.5f;
            const float parea = (prr2 - prl) * (prb - prt);
            const int obase = h * 8;
#pragma unroll
            for (int oj = 0; oj < 8; ++oj) {
                const int o = obase + oj;
                const float al = tbs[o * 4 + 0], at = tbs[o * 4 + 1];
                const float ar = tbs[o * 4 + 2], ab = tbs[o * 4 + 3];
                float iw = fminf(ar, prr2) - fmaxf(al, prl); iw = fmaxf(iw, 0.f);
                float ih = fminf(ab, prb) - fmaxf(at, prt); ih = fmaxf(ih, 0.f);
                const float inter = iw * ih;
                const float aarea = (ar - al) * (ab - at);
                const float iou = inter / (aarea + parea - inter);
                if (iou > bv) { bv = iou; bi = o; }
            }
            const float ov = __shfl_xor(bv, 1, 64);
            const int oi = __shfl_xor(bi, 1, 64);
            // first-max across halves: larger IoU wins; tie -> smaller o
            if (ov > bv || (ov == bv && oi < bi)) { bv = ov; bi = oi; }
        }

        if (h == 0 && rok) {
            const float bg = (c0 == 0) ? v[0].x : (c0 == 1) ? v[0].y
                           : (c0 == 2) ? v[0].z : v[0].w;  // slot1 comp c0
            int o_f = -1;
#pragma unroll
            for (int j = 0; j < NO; ++j)
                if (p == p16[j]) o_f = j;   // ascending j = last-o-wins
            const bool forced = (o_f >= 0);
            const bool pos = forced || (bv >= THRESH_F);
            const int o = forced ? o_f : bi;
            lr[bbase + p] = pos ? 0.f : (lse - bg);
            if (pos) {
                my_np += 1;
                const float* rowp = (const float*)(cur + 340 * rho);
                const int lbl = tlabels[b * NO + o] + 1;
                my_ce += lse - rowp[4 + lbl];
                const float4 pq = *((const float4*)priors + p);
                const float tx0 = tbs[o * 4 + 0];
                const float ty0 = tbs[o * 4 + 1];
                const float tx1 = tbs[o * 4 + 2];
                const float ty1 = tbs[o * 4 + 3];
                const float g0 = ((tx0 + tx1) * 0.5f - pq.x) / (VAR0_F * pq.z);
                const float g1 = ((ty0 + ty1) * 0.5f - pq.y) / (VAR0_F * pq.w);
                const float g2 = __logf((tx1 - tx0) / pq.z) / VAR1_F;
                const float g3 = __logf((ty1 - ty0) / pq.w) / VAR1_F;
                float dd, ad;
                dd = rowp[0] - g0; ad = fabsf(dd); my_ll += (ad < 1.f) ? 0.5f * dd * dd : (ad - 0.5f);
                dd = rowp[1] - g1; ad = fabsf(dd); my_ll += (ad < 1.f) ? 0.5f * dd * dd : (ad - 0.5f);
                dd = rowp[2] - g2; ad = fabsf(dd); my_ll += (ad < 1.f) ? 0.5f * dd * dd : (ad - 0.5f);
                dd = rowp[3] - g3; ad = fabsf(dd); my_ll += (ad < 1.f) ? 0.5f * dd * dd : (ad - 0.5f);
            }
        }

        if (have_next)
            stage_write(nxt, vreg, lane);    // write late (vmcnt drain here)

        chunk = next_chunk;
        next_chunk += SPB2;
        char* tmp = cur; cur = nxt; nxt = tmp;
    }

    for (int d2 = 1; d2 < 64; d2 <<= 1) {
        my_ll += __shfl_xor(my_ll, d2, 64);
        my_ce += __shfl_xor(my_ce, d2, 64);
        my_np += __shfl_xor(my_np, d2, 64);
    }
    if (lane == 0) {
        if (my_ll != 0.f) atomicAdd(&accB[b * 2 + 0], my_ll);
        if (my_ce != 0.f) atomicAdd(&accB[b * 2 + 1], my_ce);
        if (my_np) atomicAdd(&npos[b], my_np);
    }
}

// ---------------------------------------------------------------- select
// R17: register-cached rows, sub-slot hist16 (4-way max conflict), uint4
// zero + merge. Last-finishing block computes final outputs.
__global__ __launch_bounds__(1024) void k_select(
    const float* __restrict__ lrk, const int* __restrict__ npos,
    float* __restrict__ accB, int* __restrict__ done, float* __restrict__ out) {
    const int b = blockIdx.x;
    const float4* row4 = (const float4*)(lrk + (size_t)b * NP);
    const int tid = threadIdx.x;
    const int lane = tid & 63;
    const int wid = tid >> 6;
    const int sub = lane & 15;

    __shared__ unsigned hist16[2048][16];  // 128 KiB, [bin][sub]
    __shared__ unsigned chist[2048];       // 8 KiB
    __shared__ int sh_bucket, sh_knew;
    __shared__ float wsum[16];
    __shared__ int wcnt[16];

    float4 cch[7];
    bool cvz[7];
#pragma unroll
    for (int j = 0; j < 7; ++j) {
        const int i = tid + j * 1024;
        cvz[j] = (i < NP / 4);
        cch[j] = cvz[j] ? row4[i] : make_float4(0.f, 0.f, 0.f, 0.f);
    }

    const int K0 = min(npos[b] * NEGPOS_I, NP);
    int k = K0;
    unsigned prefix = 0;

    const int shifts[3] = {21, 10, 0};
    const unsigned masks[3] = {0u, 0xFFE00000u, 0xFFFFFC00u};

    for (int pass = 0; pass < 3; ++pass) {
        const int shift = shifts[pass];
        const unsigned mask_hi = masks[pass];
        {
            uint4* hz = (uint4*)hist16;
            for (int j = tid; j < 2048 * 4; j += 1024)
                hz[j] = make_uint4(0u, 0u, 0u, 0u);
        }
        __syncthreads();
#pragma unroll
        for (int j = 0; j < 7; ++j) {
            if (cvz[j]) {
                const float4 v4 = cch[j];
#pragma unroll
                for (int c = 0; c < 4; ++c) {
                    const float f = (c == 0) ? v4.x : (c == 1) ? v4.y
                                  : (c == 2) ? v4.z : v4.w;
                    const unsigned v = __float_as_uint(f);
                    if ((v & mask_hi) == (prefix & mask_hi))
                        atomicAdd(&hist16[(v >> shift) & 2047u][sub], 1u);
                }
            }
        }
        __syncthreads();
        for (int j = tid; j < 2048; j += 1024) {
            const uint4* hp = (const uint4*)&hist16[j][0];
            const uint4 a = hp[0], b4 = hp[1], c4 = hp[2], d4 = hp[3];
            chist[j] = a.x + a.y + a.z + a.w + b4.x + b4.y + b4.z + b4.w +
                       c4.x + c4.y + c4.z + c4.w + d4.x + d4.y + d4.z + d4.w;
        }
        __syncthreads();
        if (tid < 64) {
            unsigned g = 0;
            for (int j = 0; j < 32; ++j) g += chist[lane * 32 + j];
            unsigned T = g;
            for (int d = 1; d < 64; d <<= 1) {
                const unsigned t = __shfl_down(T, d, 64);
                if (lane + d < 64) T += t;
            }
            const unsigned E = T - g;
            const bool hit = (E < (unsigned)k) && ((unsigned)k <= T);
            const unsigned long long msk = __ballot(hit);
            const int wl = __ffsll(msk) - 1;
            if (lane == wl) {
                unsigned cum = E;
                int bsel = lane * 32, kn = k;
                for (int j = 31; j >= 0; --j) {
                    const unsigned c = chist[lane * 32 + j];
                    if (cum + c >= (unsigned)k) {
                        bsel = lane * 32 + j;
                        kn = k - (int)cum;
                        break;
                    }
                    cum += c;
                }
                sh_bucket = bsel;
                sh_knew = kn;
            }
        }
        __syncthreads();
        prefix |= ((unsigned)sh_bucket) << shift;
        k = sh_knew;
        __syncthreads();
    }
    const float T = __uint_as_float(prefix);

    float msum = 0.f;
    int mcnt = 0;
#pragma unroll
    for (int j = 0; j < 7; ++j) {
        if (cvz[j]) {
            const float4 v4 = cch[j];
#pragma unroll
            for (int c = 0; c < 4; ++c) {
                const float f = (c == 0) ? v4.x : (c == 1) ? v4.y
                              : (c == 2) ? v4.z : v4.w;
                if (__float_as_uint(f) > prefix) { msum += f; mcnt++; }
            }
        }
    }
    for (int s = 32; s > 0; s >>= 1) {
        msum += __shfl_down(msum, s, 64);
        mcnt += __shfl_down(mcnt, s, 64);
    }
    if (lane == 0) { wsum[wid] = msum; wcnt[wid] = mcnt; }
    __syncthreads();
    if (tid == 0) {
        float tot = 0.f;
        int cnt = 0;
        for (int w = 0; w < 16; ++w) { tot += wsum[w]; cnt += wcnt[w]; }
        atomicAdd(&accB[b * 2 + 1], tot + (float)(K0 - cnt) * T);
        __threadfence();
        if (atomicAdd(done, 1) == NB - 1) {   // merged k_final
            volatile const float* va = accB;
            volatile const int* vn = npos;
            int n = 0;
            float a0 = 0.f, a1 = 0.f;
            for (int bb = 0; bb < NB; ++bb) {
                n += vn[bb];
                a0 += va[bb * 2 + 0];
                a1 += va[bb * 2 + 1];
            }
            const float N = (float)n;
            out[0] = a0 / N;
            out[1] = a1 / N;
        }
    }
}

extern "C" void kernel_launch(void* const* d_in, const int* in_sizes, int n_in,
                              void* d_out, int out_size, void* d_ws, size_t ws_size,
                              hipStream_t stream) {
    const float* pred   = (const float*)d_in[0];
    const float* tboxes = (const float*)d_in[1];
    const int*   tlabels = (const int*)d_in[2];
    const float* priors = (const float*)d_in[3];
    float* out = (float*)d_out;

    char* w = (char*)d_ws;
    float*  lrk = (float*)(w + 8ull * BPCNT);         // 4*BPCNT bytes
    u64*    mcand = (u64*)(w + 12ull * BPCNT);        // NB*NO*MBLK2 u64 (100 KB)
    char*   w2 = w + 12ull * BPCNT + 8ull * NB * NO * MBLK2;
    int*    npos = (int*)w2;                          // NB i32
    float*  accB = (float*)(w2 + 4ull * NB);          // NB*2 f32
    int*    done = (int*)(w2 + 4ull * NB + 8ull * NB); // 1 i32

    k_match<<<dim3(MBLK2, NB), dim3(256), 0, stream>>>(
        tboxes, priors, mcand, npos, accB, done);
    k_main<<<dim3(SPB2, NB), dim3(64), 0, stream>>>(
        pred, tboxes, tlabels, priors, mcand, lrk, npos, accB);
    k_select<<<dim3(NB), dim3(1024), 0, stream>>>(lrk, npos, accB, done, out);
}